// Round 3
// baseline (3714.777 us; speedup 1.0000x reference)
//
#include <hip/hip_runtime.h>
#include <cstdint>
#include <cstddef>

#define H_  16
#define V_  8
#define DH_ 128
#define B_  4096
#define BT  16      // batch rows per block (16 -> ~17.9 KB LDS -> 8 blocks/CU)
#define LDST 132    // padded LDS row stride (floats)

// ---------------------------------------------------------------------------
// Kernel A: precompute M[h] = Wq[h]^T @ Wk[h]   (layout M[h][d][d'])
//           and      NT[h] = (Wo[h] @ Wv[h])^T  (layout NT[h][d'][e])
// grid = 2*H*8 = 256 blocks, 256 threads.
// ---------------------------------------------------------------------------
__global__ __launch_bounds__(256) void precompute_MN(
    const float* __restrict__ Wq, const float* __restrict__ Wk,
    const float* __restrict__ Wv, const float* __restrict__ Wo,
    float* __restrict__ Mmat, float* __restrict__ NTmat)
{
    const int bx    = blockIdx.x;
    const int which = bx & 1;
    const int h     = (bx >> 1) & 15;
    const int chunk = bx >> 5;              // 0..7
    const int tid   = threadIdx.x;
    const int col   = tid & 127;
    const int r0    = chunk * 16 + (tid >> 7) * 8;

    float acc[8];
#pragma unroll
    for (int r = 0; r < 8; ++r) acc[r] = 0.f;

    if (which == 0) {
        const float* wq = Wq + h * DH_ * DH_;
        const float* wk = Wk + h * DH_ * DH_;
        for (int e = 0; e < DH_; ++e) {
            const float bk = wk[e * DH_ + col];        // coalesced
#pragma unroll
            for (int r = 0; r < 8; ++r) acc[r] += wq[e * DH_ + r0 + r] * bk;  // uniform
        }
        float* dst = Mmat + h * DH_ * DH_;
#pragma unroll
        for (int r = 0; r < 8; ++r) dst[(r0 + r) * DH_ + col] = acc[r];
    } else {
        const float* wo = Wo + h * DH_ * DH_;
        const float* wv = Wv + h * DH_ * DH_;
        for (int d = 0; d < DH_; ++d) {
            const float bv = wv[d * DH_ + col];        // coalesced
#pragma unroll
            for (int r = 0; r < 8; ++r) acc[r] += wo[(r0 + r) * DH_ + d] * bv; // uniform
        }
        float* dst = NTmat + h * DH_ * DH_;
#pragma unroll
        for (int r = 0; r < 8; ++r) dst[(size_t)col * DH_ + (r0 + r)] = acc[r]; // tiny scatter
    }
}

// ---------------------------------------------------------------------------
// Kernel B: fused per-(b,h) pipeline, BT=16 rows per block.
// grid = H * (B/BT) = 4096 blocks, 256 threads (4 waves).
// ---------------------------------------------------------------------------
__global__ __launch_bounds__(256, 8) void fused_attn(
    const float* __restrict__ iso, const float* __restrict__ view,
    const float* __restrict__ pi,
    const float* __restrict__ Mmat, const float* __restrict__ NTmat,
    float* __restrict__ out, float* __restrict__ attn_out)
{
    __shared__ float buf_s[BT][LDST];   // iso tile, later reused as ctx tile
    __shared__ float qk_s[BT][LDST];
    __shared__ float sc_s[BT][V_];      // raw scores (dot only)
    __shared__ float attn_s[BT][V_];

    const int tid = threadIdx.x;
    const int h   = blockIdx.x >> 8;           // 256 b-tiles per head
    const int b0  = (blockIdx.x & 255) * BT;

    // ---- stage iso tile: 16 rows x 128 floats, coalesced float4 loads
#pragma unroll
    for (int i = 0; i < 2; ++i) {
        const int idx = tid + i * 256;         // 512 float4 total
        const int b   = idx >> 5;              // 32 float4 per row
        const int dq  = idx & 31;
        const float4 v4 = *(const float4*)(iso + ((size_t)(b0 + b) * H_ + h) * DH_ + dq * 4);
        *(float4*)&buf_s[b][dq * 4] = v4;
    }
    __syncthreads();

    const int tx = tid & 31;                   // output-col quad (d' = tx*4..+3)
    const int ty = tid >> 5;                   // 0..7; rows ty and ty+8

    // ---- phase 1: qk[b][d'] = sum_d iso[b][d] * M[d][d']  (2 rows x 4 cols/thread)
    {
        const float* Mh = Mmat + h * DH_ * DH_ + tx * 4;
        float acc[2][4];
#pragma unroll
        for (int i = 0; i < 2; ++i)
#pragma unroll
            for (int j = 0; j < 4; ++j) acc[i][j] = 0.f;

        for (int d = 0; d < DH_; d += 4) {
            const float4 m0 = *(const float4*)(Mh + (size_t)(d + 0) * DH_);
            const float4 m1 = *(const float4*)(Mh + (size_t)(d + 1) * DH_);
            const float4 m2 = *(const float4*)(Mh + (size_t)(d + 2) * DH_);
            const float4 m3 = *(const float4*)(Mh + (size_t)(d + 3) * DH_);
#pragma unroll
            for (int i = 0; i < 2; ++i) {
                const float4 a = *(const float4*)&buf_s[ty + i * 8][d];
                acc[i][0] += a.x * m0.x + a.y * m1.x + a.z * m2.x + a.w * m3.x;
                acc[i][1] += a.x * m0.y + a.y * m1.y + a.z * m2.y + a.w * m3.y;
                acc[i][2] += a.x * m0.z + a.y * m1.z + a.z * m2.z + a.w * m3.z;
                acc[i][3] += a.x * m0.w + a.y * m1.w + a.z * m2.w + a.w * m3.w;
            }
        }
#pragma unroll
        for (int i = 0; i < 2; ++i)
            *(float4*)&qk_s[ty + i * 8][tx * 4] =
                make_float4(acc[i][0], acc[i][1], acc[i][2], acc[i][3]);
    }
    __syncthreads();   // qk ready; iso tile dead

    // ---- phase 2a: scores. Half-wave (32 lanes) per view row, coalesced.
    // 128 (b,v) pairs; wave w handles p = w*32 + it*2 + half, it<16
    {
        const int wv   = tid >> 6;             // wave id 0..3
        const int lane = tid & 63;
        const int half = lane >> 5;
        const int l32  = lane & 31;            // d-chunk: floats l32*4..+3
#pragma unroll 4
        for (int it = 0; it < 16; ++it) {
            const int p  = wv * 32 + it * 2 + half;
            const int bl = p >> 3;
            const int v  = p & 7;
            const float4 w = *(const float4*)(view +
                (((size_t)(b0 + bl) * H_ + h) * V_ + v) * DH_ + l32 * 4);
            const float4 q = *(const float4*)&qk_s[bl][l32 * 4];
            float s = w.x * q.x + w.y * q.y + w.z * q.z + w.w * q.w;
            s += __shfl_xor(s, 1);
            s += __shfl_xor(s, 2);
            s += __shfl_xor(s, 4);
            s += __shfl_xor(s, 8);
            s += __shfl_xor(s, 16);
            if (l32 == 0) sc_s[bl][v] = s;
        }
    }
    __syncthreads();   // raw scores ready

    // ---- phase 2a': softmax. one thread per (b, v): 16*8 = 128 active
    if (tid < BT * V_) {
        const int bl = tid >> 3;
        const int v  = tid & 7;
        float sc = sc_s[bl][v] * 0.08838834764831845f;   // 1/sqrt(128)
        sc += logf(pi[((size_t)(b0 + bl) * H_ + h) * V_ + v] + 1e-6f);

        float mx = sc;
        mx = fmaxf(mx, __shfl_xor(mx, 1));
        mx = fmaxf(mx, __shfl_xor(mx, 2));
        mx = fmaxf(mx, __shfl_xor(mx, 4));
        const float ex = expf(sc - mx);
        float sm = ex;
        sm += __shfl_xor(sm, 1);
        sm += __shfl_xor(sm, 2);
        sm += __shfl_xor(sm, 4);
        const float at = ex / sm;
        attn_s[bl][v] = at;
        attn_out[((size_t)(b0 + bl) * H_ + h) * V_ + v] = at;
    }
    __syncthreads();   // attn ready

    // ---- phase 2b: ctx[b][d'] = sum_v attn[v]*view[b,h,v,d'] -> buf_s
    {
        const int bg  = tid >> 5;              // 0..7
        const int l32 = tid & 31;
#pragma unroll
        for (int r = 0; r < 2; ++r) {
            const int b = r * 8 + bg;
            const float* vbase = view + (((size_t)(b0 + b) * H_ + h) * V_) * DH_ + l32 * 4;
            float4 c = make_float4(0.f, 0.f, 0.f, 0.f);
#pragma unroll
            for (int vv = 0; vv < V_; ++vv) {
                const float a = attn_s[b][vv];                 // LDS broadcast
                const float4 x = *(const float4*)(vbase + (size_t)vv * DH_);
                c.x += a * x.x; c.y += a * x.y; c.z += a * x.z; c.w += a * x.w;
            }
            *(float4*)&buf_s[b][l32 * 4] = c;
        }
    }
    __syncthreads();   // ctx ready

    // ---- phase 3: out[b][e] = sum_d' ctx[b][d'] * NT[d'][e]  (2 rows x 4 cols/thread)
    {
        const float* Nh = NTmat + h * DH_ * DH_ + tx * 4;
        float acc[2][4];
#pragma unroll
        for (int i = 0; i < 2; ++i)
#pragma unroll
            for (int j = 0; j < 4; ++j) acc[i][j] = 0.f;

        for (int dp = 0; dp < DH_; dp += 4) {
            const float4 n0 = *(const float4*)(Nh + (size_t)(dp + 0) * DH_);
            const float4 n1 = *(const float4*)(Nh + (size_t)(dp + 1) * DH_);
            const float4 n2 = *(const float4*)(Nh + (size_t)(dp + 2) * DH_);
            const float4 n3 = *(const float4*)(Nh + (size_t)(dp + 3) * DH_);
#pragma unroll
            for (int i = 0; i < 2; ++i) {
                const float4 a = *(const float4*)&buf_s[ty + i * 8][dp];
                acc[i][0] += a.x * n0.x + a.y * n1.x + a.z * n2.x + a.w * n3.x;
                acc[i][1] += a.x * n0.y + a.y * n1.y + a.z * n2.y + a.w * n3.y;
                acc[i][2] += a.x * n0.z + a.y * n1.z + a.z * n2.z + a.w * n3.z;
                acc[i][3] += a.x * n0.w + a.y * n1.w + a.z * n2.w + a.w * n3.w;
            }
        }
#pragma unroll
        for (int i = 0; i < 2; ++i)
            *(float4*)(out + ((size_t)(b0 + ty + i * 8) * H_ + h) * DH_ + tx * 4) =
                make_float4(acc[i][0], acc[i][1], acc[i][2], acc[i][3]);
    }
}

// ---------------------------------------------------------------------------
extern "C" void kernel_launch(void* const* d_in, const int* in_sizes, int n_in,
                              void* d_out, int out_size, void* d_ws, size_t ws_size,
                              hipStream_t stream)
{
    const float* iso  = (const float*)d_in[0];   // [B,H,DH]
    const float* view = (const float*)d_in[1];   // [B,H,V,DH]
    const float* pi   = (const float*)d_in[2];   // [B,H,V]
    const float* Wq   = (const float*)d_in[3];   // [H,DH,DH]
    const float* Wk   = (const float*)d_in[4];
    const float* Wv   = (const float*)d_in[5];
    const float* Wo   = (const float*)d_in[6];

    float* out  = (float*)d_out;                           // [B,H,DH]
    float* attn = out + (size_t)B_ * H_ * DH_;             // [B,H,V]

    float* Mmat  = (float*)d_ws;                           // H*DH*DH floats (1 MB)
    float* NTmat = Mmat + (size_t)H_ * DH_ * DH_;          // H*DH*DH floats (1 MB)

    hipLaunchKernelGGL(precompute_MN, dim3(256), dim3(256), 0, stream,
                       Wq, Wk, Wv, Wo, Mmat, NTmat);
    hipLaunchKernelGGL(fused_attn, dim3(H_ * (B_ / BT)), dim3(256), 0, stream,
                       iso, view, pi, Mmat, NTmat, out, attn);
}

// Round 4
// 3637.160 us; speedup vs baseline: 1.0213x; 1.0213x over previous
//
#include <hip/hip_runtime.h>
#include <cstdint>
#include <cstddef>

#define H_  16
#define V_  8
#define DH_ 128
#define B_  4096
#define BT  16      // batch rows per block (~17.9 KB LDS)
#define LDST 132    // padded LDS row stride (floats)

// ---------------------------------------------------------------------------
// Kernel A: precompute M[h] = Wq[h]^T @ Wk[h]   (layout M[h][d][d'])
//           and      NT[h] = (Wo[h] @ Wv[h])^T  (layout NT[h][d'][e])
// grid = 2*H*8 = 256 blocks, 256 threads.
// ---------------------------------------------------------------------------
__global__ __launch_bounds__(256) void precompute_MN(
    const float* __restrict__ Wq, const float* __restrict__ Wk,
    const float* __restrict__ Wv, const float* __restrict__ Wo,
    float* __restrict__ Mmat, float* __restrict__ NTmat)
{
    const int bx    = blockIdx.x;
    const int which = bx & 1;
    const int h     = (bx >> 1) & 15;
    const int chunk = bx >> 5;              // 0..7
    const int tid   = threadIdx.x;
    const int col   = tid & 127;
    const int r0    = chunk * 16 + (tid >> 7) * 8;

    float acc[8];
#pragma unroll
    for (int r = 0; r < 8; ++r) acc[r] = 0.f;

    if (which == 0) {
        const float* wq = Wq + h * DH_ * DH_;
        const float* wk = Wk + h * DH_ * DH_;
        for (int e = 0; e < DH_; ++e) {
            const float bk = wk[e * DH_ + col];        // coalesced
#pragma unroll
            for (int r = 0; r < 8; ++r) acc[r] += wq[e * DH_ + r0 + r] * bk;  // uniform
        }
        float* dst = Mmat + h * DH_ * DH_;
#pragma unroll
        for (int r = 0; r < 8; ++r) dst[(r0 + r) * DH_ + col] = acc[r];
    } else {
        const float* wo = Wo + h * DH_ * DH_;
        const float* wv = Wv + h * DH_ * DH_;
        for (int d = 0; d < DH_; ++d) {
            const float bv = wv[d * DH_ + col];        // coalesced
#pragma unroll
            for (int r = 0; r < 8; ++r) acc[r] += wo[(r0 + r) * DH_ + d] * bv; // uniform
        }
        float* dst = NTmat + h * DH_ * DH_;
#pragma unroll
        for (int r = 0; r < 8; ++r) dst[(size_t)col * DH_ + (r0 + r)] = acc[r]; // tiny scatter
    }
}

// ---------------------------------------------------------------------------
// Kernel B: fused per-(b,h) pipeline, BT=16 rows per block.
// grid = H * (B/BT) = 4096 blocks, 256 threads (4 waves).
// __launch_bounds__(256,7): VGPR cap 72 (>= ~68 natural) -> 7 blocks/CU,
// 28 waves/CU, NO spills. (256,8) capped at 64 and spilled 5.8 GB to scratch.
// ---------------------------------------------------------------------------
__global__ __launch_bounds__(256, 7) void fused_attn(
    const float* __restrict__ iso, const float* __restrict__ view,
    const float* __restrict__ pi,
    const float* __restrict__ Mmat, const float* __restrict__ NTmat,
    float* __restrict__ out, float* __restrict__ attn_out)
{
    __shared__ float buf_s[BT][LDST];   // iso tile, later reused as ctx tile
    __shared__ float qk_s[BT][LDST];
    __shared__ float sc_s[BT][V_];      // raw scores (dot only)
    __shared__ float attn_s[BT][V_];

    const int tid = threadIdx.x;
    const int h   = blockIdx.x >> 8;           // 256 b-tiles per head
    const int b0  = (blockIdx.x & 255) * BT;

    // ---- stage iso tile: 16 rows x 128 floats, coalesced float4 loads
#pragma unroll
    for (int i = 0; i < 2; ++i) {
        const int idx = tid + i * 256;         // 512 float4 total
        const int b   = idx >> 5;              // 32 float4 per row
        const int dq  = idx & 31;
        const float4 v4 = *(const float4*)(iso + ((size_t)(b0 + b) * H_ + h) * DH_ + dq * 4);
        *(float4*)&buf_s[b][dq * 4] = v4;
    }
    __syncthreads();

    const int tx = tid & 31;                   // output-col quad (d' = tx*4..+3)
    const int ty = tid >> 5;                   // 0..7; rows ty and ty+8

    // ---- phase 1: qk[b][d'] = sum_d iso[b][d] * M[d][d']  (2 rows x 4 cols/thread)
    {
        const float* Mh = Mmat + h * DH_ * DH_ + tx * 4;
        float acc[2][4];
#pragma unroll
        for (int i = 0; i < 2; ++i)
#pragma unroll
            for (int j = 0; j < 4; ++j) acc[i][j] = 0.f;

        for (int d = 0; d < DH_; d += 4) {
            const float4 m0 = *(const float4*)(Mh + (size_t)(d + 0) * DH_);
            const float4 m1 = *(const float4*)(Mh + (size_t)(d + 1) * DH_);
            const float4 m2 = *(const float4*)(Mh + (size_t)(d + 2) * DH_);
            const float4 m3 = *(const float4*)(Mh + (size_t)(d + 3) * DH_);
#pragma unroll
            for (int i = 0; i < 2; ++i) {
                const float4 a = *(const float4*)&buf_s[ty + i * 8][d];
                acc[i][0] += a.x * m0.x + a.y * m1.x + a.z * m2.x + a.w * m3.x;
                acc[i][1] += a.x * m0.y + a.y * m1.y + a.z * m2.y + a.w * m3.y;
                acc[i][2] += a.x * m0.z + a.y * m1.z + a.z * m2.z + a.w * m3.z;
                acc[i][3] += a.x * m0.w + a.y * m1.w + a.z * m2.w + a.w * m3.w;
            }
        }
#pragma unroll
        for (int i = 0; i < 2; ++i)
            *(float4*)&qk_s[ty + i * 8][tx * 4] =
                make_float4(acc[i][0], acc[i][1], acc[i][2], acc[i][3]);
    }
    __syncthreads();   // qk ready; iso tile dead

    // ---- phase 2a: scores. Half-wave (32 lanes) per view row, coalesced.
    // 128 (b,v) pairs; wave w handles p = w*32 + it*2 + half, it<16
    {
        const int wv   = tid >> 6;             // wave id 0..3
        const int lane = tid & 63;
        const int half = lane >> 5;
        const int l32  = lane & 31;            // d-chunk: floats l32*4..+3
#pragma unroll 4
        for (int it = 0; it < 16; ++it) {
            const int p  = wv * 32 + it * 2 + half;
            const int bl = p >> 3;
            const int v  = p & 7;
            const float4 w = *(const float4*)(view +
                (((size_t)(b0 + bl) * H_ + h) * V_ + v) * DH_ + l32 * 4);
            const float4 q = *(const float4*)&qk_s[bl][l32 * 4];
            float s = w.x * q.x + w.y * q.y + w.z * q.z + w.w * q.w;
            s += __shfl_xor(s, 1);
            s += __shfl_xor(s, 2);
            s += __shfl_xor(s, 4);
            s += __shfl_xor(s, 8);
            s += __shfl_xor(s, 16);
            if (l32 == 0) sc_s[bl][v] = s;
        }
    }
    __syncthreads();   // raw scores ready

    // ---- phase 2a': softmax. one thread per (b, v): 16*8 = 128 active
    if (tid < BT * V_) {
        const int bl = tid >> 3;
        const int v  = tid & 7;
        float sc = sc_s[bl][v] * 0.08838834764831845f;   // 1/sqrt(128)
        sc += logf(pi[((size_t)(b0 + bl) * H_ + h) * V_ + v] + 1e-6f);

        float mx = sc;
        mx = fmaxf(mx, __shfl_xor(mx, 1));
        mx = fmaxf(mx, __shfl_xor(mx, 2));
        mx = fmaxf(mx, __shfl_xor(mx, 4));
        const float ex = expf(sc - mx);
        float sm = ex;
        sm += __shfl_xor(sm, 1);
        sm += __shfl_xor(sm, 2);
        sm += __shfl_xor(sm, 4);
        const float at = ex / sm;
        attn_s[bl][v] = at;
        attn_out[((size_t)(b0 + bl) * H_ + h) * V_ + v] = at;
    }
    __syncthreads();   // attn ready

    // ---- phase 2b: ctx[b][d'] = sum_v attn[v]*view[b,h,v,d'] -> buf_s
    {
        const int bg  = tid >> 5;              // 0..7
        const int l32 = tid & 31;
#pragma unroll
        for (int r = 0; r < 2; ++r) {
            const int b = r * 8 + bg;
            const float* vbase = view + (((size_t)(b0 + b) * H_ + h) * V_) * DH_ + l32 * 4;
            float4 c = make_float4(0.f, 0.f, 0.f, 0.f);
#pragma unroll
            for (int vv = 0; vv < V_; ++vv) {
                const float a = attn_s[b][vv];                 // LDS broadcast
                const float4 x = *(const float4*)(vbase + (size_t)vv * DH_);
                c.x += a * x.x; c.y += a * x.y; c.z += a * x.z; c.w += a * x.w;
            }
            *(float4*)&buf_s[b][l32 * 4] = c;
        }
    }
    __syncthreads();   // ctx ready

    // ---- phase 3: out[b][e] = sum_d' ctx[b][d'] * NT[d'][e]  (2 rows x 4 cols/thread)
    {
        const float* Nh = NTmat + h * DH_ * DH_ + tx * 4;
        float acc[2][4];
#pragma unroll
        for (int i = 0; i < 2; ++i)
#pragma unroll
            for (int j = 0; j < 4; ++j) acc[i][j] = 0.f;

        for (int dp = 0; dp < DH_; dp += 4) {
            const float4 n0 = *(const float4*)(Nh + (size_t)(dp + 0) * DH_);
            const float4 n1 = *(const float4*)(Nh + (size_t)(dp + 1) * DH_);
            const float4 n2 = *(const float4*)(Nh + (size_t)(dp + 2) * DH_);
            const float4 n3 = *(const float4*)(Nh + (size_t)(dp + 3) * DH_);
#pragma unroll
            for (int i = 0; i < 2; ++i) {
                const float4 a = *(const float4*)&buf_s[ty + i * 8][dp];
                acc[i][0] += a.x * n0.x + a.y * n1.x + a.z * n2.x + a.w * n3.x;
                acc[i][1] += a.x * n0.y + a.y * n1.y + a.z * n2.y + a.w * n3.y;
                acc[i][2] += a.x * n0.z + a.y * n1.z + a.z * n2.z + a.w * n3.z;
                acc[i][3] += a.x * n0.w + a.y * n1.w + a.z * n2.w + a.w * n3.w;
            }
        }
#pragma unroll
        for (int i = 0; i < 2; ++i)
            *(float4*)(out + ((size_t)(b0 + ty + i * 8) * H_ + h) * DH_ + tx * 4) =
                make_float4(acc[i][0], acc[i][1], acc[i][2], acc[i][3]);
    }
}

// ---------------------------------------------------------------------------
extern "C" void kernel_launch(void* const* d_in, const int* in_sizes, int n_in,
                              void* d_out, int out_size, void* d_ws, size_t ws_size,
                              hipStream_t stream)
{
    const float* iso  = (const float*)d_in[0];   // [B,H,DH]
    const float* view = (const float*)d_in[1];   // [B,H,V,DH]
    const float* pi   = (const float*)d_in[2];   // [B,H,V]
    const float* Wq   = (const float*)d_in[3];   // [H,DH,DH]
    const float* Wk   = (const float*)d_in[4];
    const float* Wv   = (const float*)d_in[5];
    const float* Wo   = (const float*)d_in[6];

    float* out  = (float*)d_out;                           // [B,H,DH]
    float* attn = out + (size_t)B_ * H_ * DH_;             // [B,H,V]

    float* Mmat  = (float*)d_ws;                           // H*DH*DH floats (1 MB)
    float* NTmat = Mmat + (size_t)H_ * DH_ * DH_;          // H*DH*DH floats (1 MB)

    hipLaunchKernelGGL(precompute_MN, dim3(256), dim3(256), 0, stream,
                       Wq, Wk, Wv, Wo, Mmat, NTmat);
    hipLaunchKernelGGL(fused_attn, dim3(H_ * (B_ / BT)), dim3(256), 0, stream,
                       iso, view, pi, Mmat, NTmat, out, attn);
}

// Round 5
// 713.054 us; speedup vs baseline: 5.2097x; 5.1008x over previous
//
#include <hip/hip_runtime.h>
#include <cstdint>
#include <cstddef>

#define H_  16
#define V_  8
#define DH_ 128
#define B_  4096
#define BT  16      // batch rows per block (~17.9 KB LDS -> up to 8 blocks/CU)
#define LDST 132    // padded LDS row stride (floats)

// ---------------------------------------------------------------------------
// Kernel A: precompute M[h] = Wq[h]^T @ Wk[h]   (layout M[h][d][d'])
//           and      NT[h] = (Wo[h] @ Wv[h])^T  (layout NT[h][d'][e])
// grid = 2*H*8 = 256 blocks, 256 threads.
// ---------------------------------------------------------------------------
__global__ __launch_bounds__(256) void precompute_MN(
    const float* __restrict__ Wq, const float* __restrict__ Wk,
    const float* __restrict__ Wv, const float* __restrict__ Wo,
    float* __restrict__ Mmat, float* __restrict__ NTmat)
{
    const int bx    = blockIdx.x;
    const int which = bx & 1;
    const int h     = (bx >> 1) & 15;
    const int chunk = bx >> 5;              // 0..7
    const int tid   = threadIdx.x;
    const int col   = tid & 127;
    const int r0    = chunk * 16 + (tid >> 7) * 8;

    float acc[8];
#pragma unroll
    for (int r = 0; r < 8; ++r) acc[r] = 0.f;

    if (which == 0) {
        const float* wq = Wq + h * DH_ * DH_;
        const float* wk = Wk + h * DH_ * DH_;
        for (int e = 0; e < DH_; ++e) {
            const float bk = wk[e * DH_ + col];        // coalesced
#pragma unroll
            for (int r = 0; r < 8; ++r) acc[r] += wq[e * DH_ + r0 + r] * bk;  // uniform
        }
        float* dst = Mmat + h * DH_ * DH_;
#pragma unroll
        for (int r = 0; r < 8; ++r) dst[(r0 + r) * DH_ + col] = acc[r];
    } else {
        const float* wo = Wo + h * DH_ * DH_;
        const float* wv = Wv + h * DH_ * DH_;
        for (int d = 0; d < DH_; ++d) {
            const float bv = wv[d * DH_ + col];        // coalesced
#pragma unroll
            for (int r = 0; r < 8; ++r) acc[r] += wo[(r0 + r) * DH_ + d] * bv; // uniform
        }
        float* dst = NTmat + h * DH_ * DH_;
#pragma unroll
        for (int r = 0; r < 8; ++r) dst[(size_t)col * DH_ + (r0 + r)] = acc[r]; // tiny scatter
    }
}

// ---------------------------------------------------------------------------
// Kernel B: fused per-(b,h) pipeline, BT=16 rows per block.
// grid = H * (B/BT) = 4096 blocks, 256 threads (4 waves).
// NOTE: no min-waves arg. (256,8) and (256,7) both capped VGPRs below the
// kernel's ~68 natural allocation and spilled 5.6+ GB to scratch (16x slowdown,
// R3/R4). Natural allocation here is ~56-68 VGPR -> 7-8 blocks/CU via LDS.
// ---------------------------------------------------------------------------
__global__ __launch_bounds__(256) void fused_attn(
    const float* __restrict__ iso, const float* __restrict__ view,
    const float* __restrict__ pi,
    const float* __restrict__ Mmat, const float* __restrict__ NTmat,
    float* __restrict__ out, float* __restrict__ attn_out)
{
    __shared__ float buf_s[BT][LDST];   // iso tile, later reused as ctx tile
    __shared__ float qk_s[BT][LDST];
    __shared__ float sc_s[BT][V_];      // raw scores (dot only)
    __shared__ float attn_s[BT][V_];

    const int tid = threadIdx.x;
    const int h   = blockIdx.x >> 8;           // 256 b-tiles per head
    const int b0  = (blockIdx.x & 255) * BT;

    // ---- stage iso tile: 16 rows x 128 floats, coalesced float4 loads
#pragma unroll
    for (int i = 0; i < 2; ++i) {
        const int idx = tid + i * 256;         // 512 float4 total
        const int b   = idx >> 5;              // 32 float4 per row
        const int dq  = idx & 31;
        const float4 v4 = *(const float4*)(iso + ((size_t)(b0 + b) * H_ + h) * DH_ + dq * 4);
        *(float4*)&buf_s[b][dq * 4] = v4;
    }
    __syncthreads();

    const int tx = tid & 31;                   // output-col quad (d' = tx*4..+3)
    const int ty = tid >> 5;                   // 0..7; rows ty and ty+8

    // ---- phase 1: qk[b][d'] = sum_d iso[b][d] * M[d][d']  (2 rows x 4 cols/thread)
    {
        const float* Mh = Mmat + h * DH_ * DH_ + tx * 4;
        float acc[2][4];
#pragma unroll
        for (int i = 0; i < 2; ++i)
#pragma unroll
            for (int j = 0; j < 4; ++j) acc[i][j] = 0.f;

        for (int d = 0; d < DH_; d += 4) {
            const float4 m0 = *(const float4*)(Mh + (size_t)(d + 0) * DH_);
            const float4 m1 = *(const float4*)(Mh + (size_t)(d + 1) * DH_);
            const float4 m2 = *(const float4*)(Mh + (size_t)(d + 2) * DH_);
            const float4 m3 = *(const float4*)(Mh + (size_t)(d + 3) * DH_);
#pragma unroll
            for (int i = 0; i < 2; ++i) {
                const float4 a = *(const float4*)&buf_s[ty + i * 8][d];
                acc[i][0] += a.x * m0.x + a.y * m1.x + a.z * m2.x + a.w * m3.x;
                acc[i][1] += a.x * m0.y + a.y * m1.y + a.z * m2.y + a.w * m3.y;
                acc[i][2] += a.x * m0.z + a.y * m1.z + a.z * m2.z + a.w * m3.z;
                acc[i][3] += a.x * m0.w + a.y * m1.w + a.z * m2.w + a.w * m3.w;
            }
        }
#pragma unroll
        for (int i = 0; i < 2; ++i)
            *(float4*)&qk_s[ty + i * 8][tx * 4] =
                make_float4(acc[i][0], acc[i][1], acc[i][2], acc[i][3]);
    }
    __syncthreads();   // qk ready; iso tile dead

    // ---- phase 2a: scores. Half-wave (32 lanes) per view row, coalesced.
    // 128 (b,v) pairs; wave w handles p = w*32 + it*2 + half, it<16
    {
        const int wv   = tid >> 6;             // wave id 0..3
        const int lane = tid & 63;
        const int half = lane >> 5;
        const int l32  = lane & 31;            // d-chunk: floats l32*4..+3
#pragma unroll 4
        for (int it = 0; it < 16; ++it) {
            const int p  = wv * 32 + it * 2 + half;
            const int bl = p >> 3;
            const int v  = p & 7;
            const float4 w = *(const float4*)(view +
                (((size_t)(b0 + bl) * H_ + h) * V_ + v) * DH_ + l32 * 4);
            const float4 q = *(const float4*)&qk_s[bl][l32 * 4];
            float s = w.x * q.x + w.y * q.y + w.z * q.z + w.w * q.w;
            s += __shfl_xor(s, 1);
            s += __shfl_xor(s, 2);
            s += __shfl_xor(s, 4);
            s += __shfl_xor(s, 8);
            s += __shfl_xor(s, 16);
            if (l32 == 0) sc_s[bl][v] = s;
        }
    }
    __syncthreads();   // raw scores ready

    // ---- phase 2a': softmax. one thread per (b, v): 16*8 = 128 active
    if (tid < BT * V_) {
        const int bl = tid >> 3;
        const int v  = tid & 7;
        float sc = sc_s[bl][v] * 0.08838834764831845f;   // 1/sqrt(128)
        sc += logf(pi[((size_t)(b0 + bl) * H_ + h) * V_ + v] + 1e-6f);

        float mx = sc;
        mx = fmaxf(mx, __shfl_xor(mx, 1));
        mx = fmaxf(mx, __shfl_xor(mx, 2));
        mx = fmaxf(mx, __shfl_xor(mx, 4));
        const float ex = expf(sc - mx);
        float sm = ex;
        sm += __shfl_xor(sm, 1);
        sm += __shfl_xor(sm, 2);
        sm += __shfl_xor(sm, 4);
        const float at = ex / sm;
        attn_s[bl][v] = at;
        attn_out[((size_t)(b0 + bl) * H_ + h) * V_ + v] = at;
    }
    __syncthreads();   // attn ready

    // ---- phase 2b: ctx[b][d'] = sum_v attn[v]*view[b,h,v,d'] -> buf_s
    {
        const int bg  = tid >> 5;              // 0..7
        const int l32 = tid & 31;
#pragma unroll
        for (int r = 0; r < 2; ++r) {
            const int b = r * 8 + bg;
            const float* vbase = view + (((size_t)(b0 + b) * H_ + h) * V_) * DH_ + l32 * 4;
            float4 c = make_float4(0.f, 0.f, 0.f, 0.f);
#pragma unroll
            for (int vv = 0; vv < V_; ++vv) {
                const float a = attn_s[b][vv];                 // LDS broadcast
                const float4 x = *(const float4*)(vbase + (size_t)vv * DH_);
                c.x += a * x.x; c.y += a * x.y; c.z += a * x.z; c.w += a * x.w;
            }
            *(float4*)&buf_s[b][l32 * 4] = c;
        }
    }
    __syncthreads();   // ctx ready

    // ---- phase 3: out[b][e] = sum_d' ctx[b][d'] * NT[d'][e]  (2 rows x 4 cols/thread)
    {
        const float* Nh = NTmat + h * DH_ * DH_ + tx * 4;
        float acc[2][4];
#pragma unroll
        for (int i = 0; i < 2; ++i)
#pragma unroll
            for (int j = 0; j < 4; ++j) acc[i][j] = 0.f;

        for (int dp = 0; dp < DH_; dp += 4) {
            const float4 n0 = *(const float4*)(Nh + (size_t)(dp + 0) * DH_);
            const float4 n1 = *(const float4*)(Nh + (size_t)(dp + 1) * DH_);
            const float4 n2 = *(const float4*)(Nh + (size_t)(dp + 2) * DH_);
            const float4 n3 = *(const float4*)(Nh + (size_t)(dp + 3) * DH_);
#pragma unroll
            for (int i = 0; i < 2; ++i) {
                const float4 a = *(const float4*)&buf_s[ty + i * 8][dp];
                acc[i][0] += a.x * n0.x + a.y * n1.x + a.z * n2.x + a.w * n3.x;
                acc[i][1] += a.x * n0.y + a.y * n1.y + a.z * n2.y + a.w * n3.y;
                acc[i][2] += a.x * n0.z + a.y * n1.z + a.z * n2.z + a.w * n3.z;
                acc[i][3] += a.x * n0.w + a.y * n1.w + a.z * n2.w + a.w * n3.w;
            }
        }
#pragma unroll
        for (int i = 0; i < 2; ++i)
            *(float4*)(out + ((size_t)(b0 + ty + i * 8) * H_ + h) * DH_ + tx * 4) =
                make_float4(acc[i][0], acc[i][1], acc[i][2], acc[i][3]);
    }
}

// ---------------------------------------------------------------------------
extern "C" void kernel_launch(void* const* d_in, const int* in_sizes, int n_in,
                              void* d_out, int out_size, void* d_ws, size_t ws_size,
                              hipStream_t stream)
{
    const float* iso  = (const float*)d_in[0];   // [B,H,DH]
    const float* view = (const float*)d_in[1];   // [B,H,V,DH]
    const float* pi   = (const float*)d_in[2];   // [B,H,V]
    const float* Wq   = (const float*)d_in[3];   // [H,DH,DH]
    const float* Wk   = (const float*)d_in[4];
    const float* Wv   = (const float*)d_in[5];
    const float* Wo   = (const float*)d_in[6];

    float* out  = (float*)d_out;                           // [B,H,DH]
    float* attn = out + (size_t)B_ * H_ * DH_;             // [B,H,V]

    float* Mmat  = (float*)d_ws;                           // H*DH*DH floats (1 MB)
    float* NTmat = Mmat + (size_t)H_ * DH_ * DH_;          // H*DH*DH floats (1 MB)

    hipLaunchKernelGGL(precompute_MN, dim3(256), dim3(256), 0, stream,
                       Wq, Wk, Wv, Wo, Mmat, NTmat);
    hipLaunchKernelGGL(fused_attn, dim3(H_ * (B_ / BT)), dim3(256), 0, stream,
                       iso, view, pi, Mmat, NTmat, out, attn);
}